// Round 1
// baseline (386.455 us; speedup 1.0000x reference)
//
#include <hip/hip_runtime.h>
#include <hip/hip_bf16.h>

#define DEVFN __device__ __forceinline__

DEVFN int lower_bound_i(const int* __restrict__ a, int n, int v) {
  int lo = 0, hi = n;
  while (lo < hi) { int mid = (lo + hi) >> 1; if (a[mid] < v) lo = mid + 1; else hi = mid; }
  return lo;
}

DEVFN unsigned short f2bf(float x) {
  __hip_bfloat16 h = __float2bfloat16(x);
  return *reinterpret_cast<unsigned short*>(&h);
}

__global__ __launch_bounds__(256) void build_qstart(const int* __restrict__ q_idx, int E, int Q,
                                                    int* __restrict__ q_start) {
  int q = blockIdx.x * blockDim.x + threadIdx.x;
  if (q <= Q) q_start[q] = lower_bound_i(q_idx, E, q);
}

// C[M x NB-tile] = A[M,K] @ B[K,NB], row-major. 128x128 tile, BK=16, 256 threads,
// 8x8 per thread (split 2x2 of 4x4). Optional bf16 output, optional bias.
template <bool OUT_BF16, bool HAS_BIAS>
__global__ __launch_bounds__(256) void gemm128(
    const float* __restrict__ A, const float* __restrict__ B,
    void* __restrict__ Cv, const float* __restrict__ bias,
    int M, int NB, int K, int ldc) {
  __shared__ float As[16][132];
  __shared__ float Bs[16][132];
  const int t = threadIdx.x;
  const int tx = t & 15, ty = t >> 4;
  const int m0 = blockIdx.y * 128, n0 = blockIdx.x * 128;

  float acc[8][8];
#pragma unroll
  for (int i = 0; i < 8; ++i)
#pragma unroll
    for (int j = 0; j < 8; ++j) acc[i][j] = 0.f;

  const int arow = t >> 1, akc = (t & 1) * 8;
  const int bkk = t >> 4, bc = (t & 15) * 8;

  for (int k0 = 0; k0 < K; k0 += 16) {
    const float* ap = A + (size_t)(m0 + arow) * K + k0 + akc;
    float4 a0 = *(const float4*)(ap);
    float4 a1 = *(const float4*)(ap + 4);
    const float* bp = B + (size_t)(k0 + bkk) * NB + n0 + bc;
    float4 b0 = *(const float4*)(bp);
    float4 b1 = *(const float4*)(bp + 4);

    As[akc + 0][arow] = a0.x; As[akc + 1][arow] = a0.y;
    As[akc + 2][arow] = a0.z; As[akc + 3][arow] = a0.w;
    As[akc + 4][arow] = a1.x; As[akc + 5][arow] = a1.y;
    As[akc + 6][arow] = a1.z; As[akc + 7][arow] = a1.w;
    *(float4*)&Bs[bkk][bc] = b0;
    *(float4*)&Bs[bkk][bc + 4] = b1;
    __syncthreads();

#pragma unroll
    for (int kk = 0; kk < 16; ++kk) {
      float4 va0 = *(const float4*)&As[kk][4 * ty];
      float4 va1 = *(const float4*)&As[kk][64 + 4 * ty];
      float4 vb0 = *(const float4*)&Bs[kk][4 * tx];
      float4 vb1 = *(const float4*)&Bs[kk][64 + 4 * tx];
      float a[8] = {va0.x, va0.y, va0.z, va0.w, va1.x, va1.y, va1.z, va1.w};
      float b[8] = {vb0.x, vb0.y, vb0.z, vb0.w, vb1.x, vb1.y, vb1.z, vb1.w};
#pragma unroll
      for (int i = 0; i < 8; ++i)
#pragma unroll
        for (int j = 0; j < 8; ++j) acc[i][j] = fmaf(a[i], b[j], acc[i][j]);
    }
    __syncthreads();
  }

#pragma unroll
  for (int ih = 0; ih < 2; ++ih)
#pragma unroll
    for (int i = 0; i < 4; ++i) {
      const int row = m0 + ih * 64 + 4 * ty + i;
#pragma unroll
      for (int jh = 0; jh < 2; ++jh) {
        const int col = n0 + jh * 64 + 4 * tx;
        float r0 = acc[ih * 4 + i][jh * 4 + 0];
        float r1 = acc[ih * 4 + i][jh * 4 + 1];
        float r2 = acc[ih * 4 + i][jh * 4 + 2];
        float r3 = acc[ih * 4 + i][jh * 4 + 3];
        if (HAS_BIAS) {
          r0 += bias[col + 0]; r1 += bias[col + 1];
          r2 += bias[col + 2]; r3 += bias[col + 3];
        }
        const size_t off = (size_t)row * ldc + col;
        if (OUT_BF16) {
          ushort4 pk;
          pk.x = f2bf(r0); pk.y = f2bf(r1); pk.z = f2bf(r2); pk.w = f2bf(r3);
          *(ushort4*)((__hip_bfloat16*)Cv + off) = pk;
        } else {
          float4 pk = {r0, r1, r2, r3};
          *(float4*)((float*)Cv + off) = pk;
        }
      }
    }
}

// One block (256 thr) per query. Thread t = head(t>>5) * 32 + dim(t&31).
// Online softmax over the query's edge segment; m starts at 0 (matches
// reference max(segment_max, 0)). g added once at the end with weight
// sum(alpha) = l / max(l, 1e-8); empty segments output 0.
__global__ __launch_bounds__(256) void edge_attn(
    const int* __restrict__ s_idx, const int* __restrict__ q_start,
    const __hip_bfloat16* __restrict__ KV, const float* __restrict__ Qf,
    const float* __restrict__ Gf, float* __restrict__ out_pre,
    const float* __restrict__ log_tau) {
  const int q = blockIdx.x;
  const int t = threadIdx.x;
  const int start = q_start[q], end = q_start[q + 1];

  const float tau = __expf(log_tau[0]);
  const float rs = 1.0f / (5.656854249492381f * tau);  // 1/(sqrt(32)*tau)
  const float qv = Qf[(size_t)q * 256 + t] * rs;

  float m = 0.f, l = 0.f, o = 0.f;
  __shared__ int sbuf[256];

  for (int base = start; base < end; base += 256) {
    const int nb = min(256, end - base);
    __syncthreads();
    if (t < nb) sbuf[t] = s_idx[base + t];
    __syncthreads();
    for (int i = 0; i < nb; ++i) {
      const __hip_bfloat16* row = KV + (size_t)sbuf[i] * 512;
      float p = qv * __bfloat162float(row[t]);
      p += __shfl_xor(p, 1);
      p += __shfl_xor(p, 2);
      p += __shfl_xor(p, 4);
      p += __shfl_xor(p, 8);
      p += __shfl_xor(p, 16);
      const float nm = fmaxf(m, p);
      const float eo = __expf(m - nm);
      const float ew = __expf(p - nm);
      const float vv = __bfloat162float(row[256 + t]);
      o = o * eo + ew * vv;
      l = l * eo + ew;
      m = nm;
    }
  }
  const float inv = 1.0f / fmaxf(l, 1e-8f);
  float res = 0.f;
  if (end > start) res = o * inv + (l * inv) * Gf[(size_t)q * 256 + t];
  out_pre[(size_t)q * 256 + t] = res;
}

extern "C" void kernel_launch(void* const* d_in, const int* in_sizes, int n_in,
                              void* d_out, int out_size, void* d_ws, size_t ws_size,
                              hipStream_t stream) {
  const float* query   = (const float*)d_in[0];
  const float* support = (const float*)d_in[1];
  const float* geo     = (const float*)d_in[2];
  const int*   q_idx   = (const int*)d_in[3];
  const int*   s_idx   = (const int*)d_in[4];
  const float* Wq      = (const float*)d_in[6];
  const float* Wk      = (const float*)d_in[7];
  const float* Wv      = (const float*)d_in[8];
  const float* Wg      = (const float*)d_in[9];
  const float* Wo      = (const float*)d_in[10];
  const float* bo      = (const float*)d_in[11];
  const float* log_tau = (const float*)d_in[12];

  const int D = 256;
  const int Q = in_sizes[0] / D;   // 8192
  const int N = in_sizes[1] / D;   // 65536
  const int E = in_sizes[3];       // 262144
  const int G = in_sizes[2] / Q;   // 64

  char* ws = (char*)d_ws;
  __hip_bfloat16* KV = (__hip_bfloat16*)ws;                 // [N][512] bf16 (K | V)
  float* Qf      = (float*)(ws + (size_t)N * 512 * 2);      // [Q][256]
  float* Gf      = Qf + (size_t)Q * D;                      // [Q][256]
  float* out_pre = Gf + (size_t)Q * D;                      // [Q][256]
  int*   q_start = (int*)(out_pre + (size_t)Q * D);         // [Q+1]

  dim3 blk(256);

  // Projections: Kf,Vf -> interleaved bf16 [N][512]
  gemm128<true, false><<<dim3(D / 128, N / 128), blk, 0, stream>>>(
      support, Wk, (void*)KV, nullptr, N, D, D, 2 * D);
  gemm128<true, false><<<dim3(D / 128, N / 128), blk, 0, stream>>>(
      support, Wv, (void*)(KV + D), nullptr, N, D, D, 2 * D);
  // Qf, Gf fp32
  gemm128<false, false><<<dim3(D / 128, Q / 128), blk, 0, stream>>>(
      query, Wq, (void*)Qf, nullptr, Q, D, D, D);
  gemm128<false, false><<<dim3(D / 128, Q / 128), blk, 0, stream>>>(
      geo, Wg, (void*)Gf, nullptr, Q, D, G, D);

  build_qstart<<<dim3((Q + 256) / 256), blk, 0, stream>>>(q_idx, E, Q, q_start);

  edge_attn<<<dim3(Q), blk, 0, stream>>>(s_idx, q_start, KV, Qf, Gf, out_pre, log_tau);

  // Final: out = out_pre @ Wo + bo (fp32 out)
  gemm128<false, true><<<dim3(D / 128, Q / 128), blk, 0, stream>>>(
      out_pre, Wo, d_out, bo, Q, D, D, D);
}

// Round 2
// 192.350 us; speedup vs baseline: 2.0091x; 2.0091x over previous
//
#include <hip/hip_runtime.h>
#include <hip/hip_bf16.h>

typedef __attribute__((ext_vector_type(8))) short short8v;
typedef __attribute__((ext_vector_type(4))) float f32x4;

#define DEVFN __device__ __forceinline__

DEVFN int lower_bound_i(const int* __restrict__ a, int n, int v) {
  int lo = 0, hi = n;
  while (lo < hi) { int mid = (lo + hi) >> 1; if (a[mid] < v) lo = mid + 1; else hi = mid; }
  return lo;
}

DEVFN unsigned short f2bf(float x) {
  __hip_bfloat16 h = __float2bfloat16(x);
  return *reinterpret_cast<unsigned short*>(&h);
}

DEVFN float bf2f(unsigned short u) {
  unsigned int x = ((unsigned int)u) << 16;
  float f;
  __builtin_memcpy(&f, &x, 4);
  return f;
}

DEVFN void gload16(const void* g, void* l) {
  __builtin_amdgcn_global_load_lds(
      (const __attribute__((address_space(1))) void*)g,
      (__attribute__((address_space(3))) void*)l, 16, 0, 0);
}

__global__ __launch_bounds__(256) void build_qstart(const int* __restrict__ q_idx, int E, int Q,
                                                    int* __restrict__ q_start) {
  int q = blockIdx.x * blockDim.x + threadIdx.x;
  if (q <= Q) q_start[q] = lower_bound_i(q_idx, E, q);
}

__global__ __launch_bounds__(256) void cast_bf16(const float4* __restrict__ in,
                                                 ushort4* __restrict__ out, int n4) {
  for (int i = blockIdx.x * 256 + threadIdx.x; i < n4; i += gridDim.x * 256) {
    float4 v = in[i];
    ushort4 o;
    o.x = f2bf(v.x); o.y = f2bf(v.y); o.z = f2bf(v.z); o.w = f2bf(v.w);
    out[i] = o;
  }
}

// out[n*K+k] = bf16(W[k*N+n])  (transpose-cast, writes coalesced)
__global__ __launch_bounds__(256) void tcast(const float* __restrict__ W,
                                             unsigned short* __restrict__ out, int K, int N) {
  int id = blockIdx.x * 256 + threadIdx.x;
  if (id < N * K) {
    int n = id / K, k = id % K;
    out[id] = f2bf(W[(size_t)k * N + n]);
  }
}

// C = A(bf16 [M][K]) @ Bt(bf16 [NB][K])^T. 128x128 tile, BK=32, 4 waves (2x2),
// each wave 64x64 = 4x4 frags of mfma_f32_16x16x32_bf16.
// OUT_MODE: 0 = fp32 at row*ldc+col, 1 = bf16 at row*ldc+col,
//           2 = bf16 KV-interleaved: row*512 + (col<256 ? col*2 : (col-256)*2+1)
template <int OUT_MODE, bool HAS_BIAS>
__global__ __launch_bounds__(256) void gemm_mfma(
    const unsigned short* __restrict__ A, const unsigned short* __restrict__ Bt,
    void* __restrict__ Cv, const float* __restrict__ bias,
    int M, int NB, int K, int ldc) {
  __shared__ unsigned short As[128 * 32];
  __shared__ unsigned short Bs[128 * 32];

  const int t = threadIdx.x;
  const int wv = t >> 6;
  const int l = t & 63;
  const int wr = wv >> 1, wc = wv & 1;
  const int lr = l & 15, lk = l >> 4;

  // XCD-bijective swizzle (all launches have nwg % 8 == 0)
  const int gx = gridDim.x;
  const int nwg = gx * gridDim.y;
  const int orig = blockIdx.y * gx + blockIdx.x;
  const int cpx = nwg >> 3;
  const int swz = (orig & 7) * cpx + (orig >> 3);
  const int n0 = (swz % gx) * 128;
  const int m0 = (swz / gx) * 128;

  f32x4 acc[4][4];
#pragma unroll
  for (int m = 0; m < 4; ++m)
#pragma unroll
    for (int n = 0; n < 4; ++n) acc[m][n] = (f32x4){0.f, 0.f, 0.f, 0.f};

  const int wbase = (t & ~63) * 16;  // wave-uniform LDS byte offset for this thread's wave

  for (int k0 = 0; k0 < K; k0 += 32) {
    // stage A,B tiles: linear LDS dest, inverse-swizzled global source (rule 21)
#pragma unroll
    for (int s = 0; s < 2; ++s) {
      const int cidx = s * 256 + t;
      const int row = cidx >> 2, cc = cidx & 3;
      const int cs = cc ^ ((row >> 1) & 3);
      gload16(A + (size_t)(m0 + row) * K + k0 + cs * 8,
              (char*)As + (size_t)(s * 4096 + wbase));
      gload16(Bt + (size_t)(n0 + row) * K + k0 + cs * 8,
              (char*)Bs + (size_t)(s * 4096 + wbase));
    }
    __syncthreads();  // drains vmcnt before barrier (compiler-inserted)

    short8v a[4], b[4];
#pragma unroll
    for (int m = 0; m < 4; ++m) {
      const int row = wr * 64 + m * 16 + lr;
      const int cs = lk ^ ((row >> 1) & 3);
      a[m] = *(const short8v*)&As[row * 32 + cs * 8];
    }
#pragma unroll
    for (int n = 0; n < 4; ++n) {
      const int row = wc * 64 + n * 16 + lr;
      const int cs = lk ^ ((row >> 1) & 3);
      b[n] = *(const short8v*)&Bs[row * 32 + cs * 8];
    }
#pragma unroll
    for (int m = 0; m < 4; ++m)
#pragma unroll
      for (int n = 0; n < 4; ++n)
        acc[m][n] = __builtin_amdgcn_mfma_f32_16x16x32_bf16(a[m], b[n], acc[m][n], 0, 0, 0);
    __syncthreads();
  }

  // epilogue: C/D layout col = lane&15, row = (lane>>4)*4 + reg  (m89-verified)
#pragma unroll
  for (int m = 0; m < 4; ++m)
#pragma unroll
    for (int n = 0; n < 4; ++n) {
      const f32x4 v = acc[m][n];
      const int col = n0 + wc * 64 + n * 16 + lr;
      const int rbase = m0 + wr * 64 + m * 16 + lk * 4;
      float bv = 0.f;
      if (HAS_BIAS) bv = bias[col];
#pragma unroll
      for (int r = 0; r < 4; ++r) {
        const int row = rbase + r;
        const float val = v[r] + bv;
        if (OUT_MODE == 0) {
          ((float*)Cv)[(size_t)row * ldc + col] = val;
        } else if (OUT_MODE == 1) {
          ((unsigned short*)Cv)[(size_t)row * ldc + col] = f2bf(val);
        } else {
          const size_t idx = (size_t)row * 512 + (col < 256 ? col * 2 : (col - 256) * 2 + 1);
          ((unsigned short*)Cv)[idx] = f2bf(val);
        }
      }
    }
}

// One block (256 thr) per query; head = t>>5, dim = t&31.
// KV interleaved: uint at [n*256 + t] = (k_t | v_t<<16) in bf16.
__global__ __launch_bounds__(256) void edge_attn(
    const int* __restrict__ s_idx, const int* __restrict__ q_start,
    const unsigned int* __restrict__ KVu, const unsigned short* __restrict__ Qf,
    const unsigned short* __restrict__ Gf, unsigned short* __restrict__ out_pre,
    const float* __restrict__ log_tau) {
  const int q = blockIdx.x;
  const int t = threadIdx.x;
  const int start = q_start[q], end = q_start[q + 1];

  const float tau = __expf(log_tau[0]);
  const float rs = 1.0f / (5.656854249492381f * tau);  // 1/(sqrt(32)*tau)
  const float qv = bf2f(Qf[(size_t)q * 256 + t]) * rs;

  float m = 0.f, l = 0.f, o = 0.f;
  __shared__ int sbuf[256];

  for (int base = start; base < end; base += 256) {
    const int nb = min(256, end - base);
    __syncthreads();
    if (t < nb) sbuf[t] = s_idx[base + t];
    __syncthreads();
    for (int i = 0; i < nb; ++i) {
      const unsigned int w = KVu[(size_t)sbuf[i] * 256 + t];
      const float kd = bf2f((unsigned short)(w & 0xffffu));
      const float vv = bf2f((unsigned short)(w >> 16));
      float p = qv * kd;
      p += __shfl_xor(p, 1);
      p += __shfl_xor(p, 2);
      p += __shfl_xor(p, 4);
      p += __shfl_xor(p, 8);
      p += __shfl_xor(p, 16);
      const float nm = fmaxf(m, p);
      const float eo = __expf(m - nm);
      const float ew = __expf(p - nm);
      o = o * eo + ew * vv;
      l = l * eo + ew;
      m = nm;
    }
  }
  const float inv = 1.0f / fmaxf(l, 1e-8f);
  float res = 0.f;
  if (end > start) res = o * inv + (l * inv) * bf2f(Gf[(size_t)q * 256 + t]);
  out_pre[(size_t)q * 256 + t] = f2bf(res);
}

extern "C" void kernel_launch(void* const* d_in, const int* in_sizes, int n_in,
                              void* d_out, int out_size, void* d_ws, size_t ws_size,
                              hipStream_t stream) {
  const float* query   = (const float*)d_in[0];
  const float* support = (const float*)d_in[1];
  const float* geo     = (const float*)d_in[2];
  const int*   q_idx   = (const int*)d_in[3];
  const int*   s_idx   = (const int*)d_in[4];
  const float* Wq      = (const float*)d_in[6];
  const float* Wk      = (const float*)d_in[7];
  const float* Wv      = (const float*)d_in[8];
  const float* Wg      = (const float*)d_in[9];
  const float* Wo      = (const float*)d_in[10];
  const float* bo      = (const float*)d_in[11];
  const float* log_tau = (const float*)d_in[12];

  const int D = 256;
  const int Q = in_sizes[0] / D;   // 8192
  const int N = in_sizes[1] / D;   // 65536
  const int E = in_sizes[3];       // 262144
  const int G = in_sizes[2] / Q;   // 64

  unsigned short* ws = (unsigned short*)d_ws;
  unsigned short* KV   = ws;                         // [N][512] bf16 interleaved (k,v) pairs
  unsigned short* Abf  = KV   + (size_t)N * 512;     // support bf16 [N][256]
  unsigned short* Qbf  = Abf  + (size_t)N * 256;     // query bf16 [Q][256]
  unsigned short* Gbf  = Qbf  + (size_t)Q * 256;     // geo bf16 [Q][64]
  unsigned short* Qf   = Gbf  + (size_t)Q * 64;      // bf16 [Q][256]
  unsigned short* Gf   = Qf   + (size_t)Q * 256;     // bf16 [Q][256]
  unsigned short* Opre = Gf   + (size_t)Q * 256;     // bf16 [Q][256]
  unsigned short* Btkv = Opre + (size_t)Q * 256;     // [512][256]
  unsigned short* Btq  = Btkv + 512 * 256;           // [256][256]
  unsigned short* Btg  = Btq  + 256 * 256;           // [256][64]
  unsigned short* Bto  = Btg  + 256 * 64;            // [256][256]
  int* q_start = (int*)(Bto + 256 * 256);            // [Q+1]

  dim3 blk(256);

  // casts
  cast_bf16<<<dim3(2048), blk, 0, stream>>>((const float4*)support, (ushort4*)Abf, N * D / 4);
  cast_bf16<<<dim3(2048), blk, 0, stream>>>((const float4*)query, (ushort4*)Qbf, Q * D / 4);
  cast_bf16<<<dim3(512), blk, 0, stream>>>((const float4*)geo, (ushort4*)Gbf, Q * G / 4);
  tcast<<<dim3(256), blk, 0, stream>>>(Wk, Btkv, D, D);
  tcast<<<dim3(256), blk, 0, stream>>>(Wv, Btkv + 256 * 256, D, D);
  tcast<<<dim3(256), blk, 0, stream>>>(Wq, Btq, D, D);
  tcast<<<dim3(64),  blk, 0, stream>>>(Wg, Btg, G, D);
  tcast<<<dim3(256), blk, 0, stream>>>(Wo, Bto, D, D);

  // fused K|V projection -> interleaved KV
  gemm_mfma<2, false><<<dim3(512 / 128, N / 128), blk, 0, stream>>>(
      Abf, Btkv, (void*)KV, nullptr, N, 512, D, 0);
  // Qf, Gf (bf16 out)
  gemm_mfma<1, false><<<dim3(D / 128, Q / 128), blk, 0, stream>>>(
      Qbf, Btq, (void*)Qf, nullptr, Q, D, D, D);
  gemm_mfma<1, false><<<dim3(D / 128, Q / 128), blk, 0, stream>>>(
      Gbf, Btg, (void*)Gf, nullptr, Q, D, G, D);

  build_qstart<<<dim3((Q + 256) / 256), blk, 0, stream>>>(q_idx, E, Q, q_start);

  edge_attn<<<dim3(Q), blk, 0, stream>>>(s_idx, q_start, (const unsigned int*)KV,
                                         Qf, Gf, Opre, log_tau);

  // final: out = out_pre @ Wo + bo (fp32 out)
  gemm_mfma<0, true><<<dim3(D / 128, Q / 128), blk, 0, stream>>>(
      Opre, Bto, d_out, bo, Q, D, D, D);
}

// Round 3
// 128.572 us; speedup vs baseline: 3.0057x; 1.4960x over previous
//
#include <hip/hip_runtime.h>
#include <hip/hip_bf16.h>

typedef __attribute__((ext_vector_type(8))) short short8v;
typedef __attribute__((ext_vector_type(4))) float f32x4;

#define DEVFN __device__ __forceinline__

DEVFN unsigned short f2bf(float x) {
  __hip_bfloat16 h = __float2bfloat16(x);
  return *reinterpret_cast<unsigned short*>(&h);
}

DEVFN float bf2f(unsigned short u) {
  unsigned int x = ((unsigned int)u) << 16;
  float f;
  __builtin_memcpy(&f, &x, 4);
  return f;
}

DEVFN void gload16(const void* g, void* l) {
  __builtin_amdgcn_global_load_lds(
      (const __attribute__((address_space(1))) void*)g,
      (__attribute__((address_space(3))) void*)l, 16, 0, 0);
}

// One kernel for all preprocessing: bf16 casts of support/query/geo,
// transpose-casts of the 5 weight matrices, and q_start (binary search).
__global__ __launch_bounds__(256) void prep(
    const float* __restrict__ support, const float* __restrict__ query,
    const float* __restrict__ geo,
    const float* __restrict__ Wk, const float* __restrict__ Wv,
    const float* __restrict__ Wq, const float* __restrict__ Wo,
    const float* __restrict__ Wg,
    unsigned short* __restrict__ Abf, unsigned short* __restrict__ Qbf,
    unsigned short* __restrict__ Gbf,
    unsigned short* __restrict__ Btkv, unsigned short* __restrict__ Btq,
    unsigned short* __restrict__ Bto, unsigned short* __restrict__ Btg,
    const int* __restrict__ q_idx, int* __restrict__ q_start,
    int N, int Q, int E) {
  const int b = blockIdx.x, t = threadIdx.x;
  if (b < 2048) {                       // support cast: N*64 float4s
    const int n4 = N * 64;
    for (int i = b * 256 + t; i < n4; i += 2048 * 256) {
      float4 v = ((const float4*)support)[i];
      ushort4 o = {f2bf(v.x), f2bf(v.y), f2bf(v.z), f2bf(v.w)};
      ((ushort4*)Abf)[i] = o;
    }
  } else if (b < 2560) {                // query cast: Q*64 float4s
    const int n4 = Q * 64;
    for (int i = (b - 2048) * 256 + t; i < n4; i += 512 * 256) {
      float4 v = ((const float4*)query)[i];
      ushort4 o = {f2bf(v.x), f2bf(v.y), f2bf(v.z), f2bf(v.w)};
      ((ushort4*)Qbf)[i] = o;
    }
  } else if (b < 2688) {                // geo cast: Q*16 float4s
    const int n4 = Q * 16;
    for (int i = (b - 2560) * 256 + t; i < n4; i += 128 * 256) {
      float4 v = ((const float4*)geo)[i];
      ushort4 o = {f2bf(v.x), f2bf(v.y), f2bf(v.z), f2bf(v.w)};
      ((ushort4*)Gbf)[i] = o;
    }
  } else if (b < 2944) {                // Wk/Wv/Wq/Wo transpose-cast (256x256 each)
    const int wi = (b - 2688) >> 6, bb = (b - 2688) & 63;
    const float* W = (wi == 0) ? Wk : (wi == 1) ? Wv : (wi == 2) ? Wq : Wo;
    unsigned short* O = (wi == 0) ? Btkv : (wi == 1) ? (Btkv + 65536)
                     : (wi == 2) ? Btq : Bto;
    for (int id = bb * 256 + t; id < 65536; id += 64 * 256) {
      const int n = id >> 8, k = id & 255;
      O[id] = f2bf(W[k * 256 + n]);
    }
  } else if (b < 2960) {                // Wg transpose-cast: [64][256] -> Btg[256][64]
    for (int id = (b - 2944) * 256 + t; id < 16384; id += 16 * 256) {
      const int n = id >> 6, k = id & 63;
      Btg[id] = f2bf(Wg[k * 256 + n]);
    }
  } else {                              // q_start: lower_bound over sorted q_idx
    const int q = (b - 2960) * 256 + t;
    if (q <= Q) {
      int lo = 0, hi = E;
      while (lo < hi) { int mid = (lo + hi) >> 1; if (q_idx[mid] < q) lo = mid + 1; else hi = mid; }
      q_start[q] = lo;
    }
  }
}

// C = A(bf16 [M][K]) @ Bt(bf16 [NB][K])^T. 128x128 tile, BK=32, 4 waves (2x2),
// each wave 64x64 = 4x4 frags of mfma_f32_16x16x32_bf16.
// OUT_MODE: 0 = fp32 at row*ldc+col, 1 = bf16 at row*ldc+col,
//           2 = bf16 KV-interleaved: row*512 + (col<256 ? col*2 : (col-256)*2+1)
template <int OUT_MODE, bool HAS_BIAS>
__global__ __launch_bounds__(256) void gemm_mfma(
    const unsigned short* __restrict__ A, const unsigned short* __restrict__ Bt,
    void* __restrict__ Cv, const float* __restrict__ bias,
    int M, int NB, int K, int ldc) {
  __shared__ unsigned short As[128 * 32];
  __shared__ unsigned short Bs[128 * 32];

  const int t = threadIdx.x;
  const int wv = t >> 6;
  const int l = t & 63;
  const int wr = wv >> 1, wc = wv & 1;
  const int lr = l & 15, lk = l >> 4;

  const int gx = gridDim.x;
  const int nwg = gx * gridDim.y;
  const int orig = blockIdx.y * gx + blockIdx.x;
  const int cpx = nwg >> 3;
  const int swz = (orig & 7) * cpx + (orig >> 3);
  const int n0 = (swz % gx) * 128;
  const int m0 = (swz / gx) * 128;

  f32x4 acc[4][4];
#pragma unroll
  for (int m = 0; m < 4; ++m)
#pragma unroll
    for (int n = 0; n < 4; ++n) acc[m][n] = (f32x4){0.f, 0.f, 0.f, 0.f};

  const int wbase = (t & ~63) * 16;

  for (int k0 = 0; k0 < K; k0 += 32) {
#pragma unroll
    for (int s = 0; s < 2; ++s) {
      const int cidx = s * 256 + t;
      const int row = cidx >> 2, cc = cidx & 3;
      const int cs = cc ^ ((row >> 1) & 3);
      gload16(A + (size_t)(m0 + row) * K + k0 + cs * 8,
              (char*)As + (size_t)(s * 4096 + wbase));
      gload16(Bt + (size_t)(n0 + row) * K + k0 + cs * 8,
              (char*)Bs + (size_t)(s * 4096 + wbase));
    }
    __syncthreads();

    short8v a[4], b[4];
#pragma unroll
    for (int m = 0; m < 4; ++m) {
      const int row = wr * 64 + m * 16 + lr;
      const int cs = lk ^ ((row >> 1) & 3);
      a[m] = *(const short8v*)&As[row * 32 + cs * 8];
    }
#pragma unroll
    for (int n = 0; n < 4; ++n) {
      const int row = wc * 64 + n * 16 + lr;
      const int cs = lk ^ ((row >> 1) & 3);
      b[n] = *(const short8v*)&Bs[row * 32 + cs * 8];
    }
#pragma unroll
    for (int m = 0; m < 4; ++m)
#pragma unroll
      for (int n = 0; n < 4; ++n)
        acc[m][n] = __builtin_amdgcn_mfma_f32_16x16x32_bf16(a[m], b[n], acc[m][n], 0, 0, 0);
    __syncthreads();
  }

#pragma unroll
  for (int m = 0; m < 4; ++m)
#pragma unroll
    for (int n = 0; n < 4; ++n) {
      const f32x4 v = acc[m][n];
      const int col = n0 + wc * 64 + n * 16 + lr;
      const int rbase = m0 + wr * 64 + m * 16 + lk * 4;
      float bv = 0.f;
      if (HAS_BIAS) bv = bias[col];
#pragma unroll
      for (int r = 0; r < 4; ++r) {
        const int row = rbase + r;
        const float val = v[r] + bv;
        if (OUT_MODE == 0) {
          ((float*)Cv)[(size_t)row * ldc + col] = val;
        } else if (OUT_MODE == 1) {
          ((unsigned short*)Cv)[(size_t)row * ldc + col] = f2bf(val);
        } else {
          const size_t idx = (size_t)row * 512 + (col < 256 ? col * 2 : (col - 256) * 2 + 1);
          ((unsigned short*)Cv)[idx] = f2bf(val);
        }
      }
    }
}

// One block (256 thr = 4 waves) per query. Each wave takes every-4th edge.
// Within a wave: 8 lanes per head, 4 dims per lane (one uint4 = 4 (k,v) bf16
// pairs). No online max (exact: see analysis) -> partials merge by summation.
__global__ __launch_bounds__(256) void edge_attn(
    const int* __restrict__ s_idx, const int* __restrict__ q_start,
    const uint4* __restrict__ KV4, const unsigned short* __restrict__ Qf,
    const unsigned short* __restrict__ Gf, unsigned short* __restrict__ out_pre,
    const float* __restrict__ log_tau) {
  const int q = blockIdx.x;
  const int t = threadIdx.x;
  const int w = t >> 6;
  const int lane = t & 63;
  const int start = q_start[q], end = q_start[q + 1];

  const float tau = __expf(log_tau[0]);
  const float rs = 1.0f / (5.656854249492381f * tau);  // 1/(sqrt(32)*tau)

  ushort4 qu = *(const ushort4*)(Qf + (size_t)q * 256 + lane * 4);
  const float qv0 = bf2f(qu.x) * rs, qv1 = bf2f(qu.y) * rs;
  const float qv2 = bf2f(qu.z) * rs, qv3 = bf2f(qu.w) * rs;

  float o0 = 0.f, o1 = 0.f, o2 = 0.f, o3 = 0.f, l = 0.f;

  int i = start + w;
  if (i < end) {
    uint4 kv = KV4[(size_t)s_idx[i] * 64 + lane];
    for (;;) {
      const int inext = i + 4;
      const bool more = inext < end;
      uint4 kvn;
      if (more) kvn = KV4[(size_t)s_idx[inext] * 64 + lane];
      const float k0 = bf2f((unsigned short)(kv.x & 0xffffu));
      const float v0 = bf2f((unsigned short)(kv.x >> 16));
      const float k1 = bf2f((unsigned short)(kv.y & 0xffffu));
      const float v1 = bf2f((unsigned short)(kv.y >> 16));
      const float k2 = bf2f((unsigned short)(kv.z & 0xffffu));
      const float v2 = bf2f((unsigned short)(kv.z >> 16));
      const float k3 = bf2f((unsigned short)(kv.w & 0xffffu));
      const float v3 = bf2f((unsigned short)(kv.w >> 16));
      float p = qv0 * k0 + qv1 * k1 + qv2 * k2 + qv3 * k3;
      p += __shfl_xor(p, 1);
      p += __shfl_xor(p, 2);
      p += __shfl_xor(p, 4);   // p now = full head dot for this edge
      const float ew = __expf(p);
      l += ew;
      o0 = fmaf(ew, v0, o0);
      o1 = fmaf(ew, v1, o1);
      o2 = fmaf(ew, v2, o2);
      o3 = fmaf(ew, v3, o3);
      if (!more) break;
      i = inext;
      kv = kvn;
    }
  }

  __shared__ float o_sh[4][256];
  __shared__ float l_sh[4][8];
  *(float4*)&o_sh[w][lane * 4] = (float4){o0, o1, o2, o3};
  if ((lane & 7) == 0) l_sh[w][lane >> 3] = l;
  __syncthreads();

  const float osum = o_sh[0][t] + o_sh[1][t] + o_sh[2][t] + o_sh[3][t];
  const int h = t >> 5;
  const float lsum = l_sh[0][h] + l_sh[1][h] + l_sh[2][h] + l_sh[3][h];
  const float inv = 1.0f / fmaxf(lsum, 1e-8f);
  float res = 0.f;
  if (end > start) res = osum * inv + (lsum * inv) * bf2f(Gf[(size_t)q * 256 + t]);
  out_pre[(size_t)q * 256 + t] = f2bf(res);
}

extern "C" void kernel_launch(void* const* d_in, const int* in_sizes, int n_in,
                              void* d_out, int out_size, void* d_ws, size_t ws_size,
                              hipStream_t stream) {
  const float* query   = (const float*)d_in[0];
  const float* support = (const float*)d_in[1];
  const float* geo     = (const float*)d_in[2];
  const int*   q_idx   = (const int*)d_in[3];
  const int*   s_idx   = (const int*)d_in[4];
  const float* Wq      = (const float*)d_in[6];
  const float* Wk      = (const float*)d_in[7];
  const float* Wv      = (const float*)d_in[8];
  const float* Wg      = (const float*)d_in[9];
  const float* Wo      = (const float*)d_in[10];
  const float* bo      = (const float*)d_in[11];
  const float* log_tau = (const float*)d_in[12];

  const int D = 256;
  const int Q = in_sizes[0] / D;   // 8192
  const int N = in_sizes[1] / D;   // 65536
  const int E = in_sizes[3];       // 262144

  unsigned short* ws = (unsigned short*)d_ws;
  unsigned short* KV   = ws;                         // [N][512] bf16 interleaved (k,v)
  unsigned short* Abf  = KV   + (size_t)N * 512;     // support bf16 [N][256]
  unsigned short* Qbf  = Abf  + (size_t)N * 256;     // query bf16 [Q][256]
  unsigned short* Gbf  = Qbf  + (size_t)Q * 256;     // geo bf16 [Q][64]
  unsigned short* Qf   = Gbf  + (size_t)Q * 64;      // bf16 [Q][256]
  unsigned short* Gf   = Qf   + (size_t)Q * 256;     // bf16 [Q][256]
  unsigned short* Opre = Gf   + (size_t)Q * 256;     // bf16 [Q][256]
  unsigned short* Btkv = Opre + (size_t)Q * 256;     // [512][256]
  unsigned short* Btq  = Btkv + 512 * 256;           // [256][256]
  unsigned short* Btg  = Btq  + 256 * 256;           // [256][64]
  unsigned short* Bto  = Btg  + 256 * 64;            // [256][256]
  int* q_start = (int*)(Bto + 256 * 256);            // [Q+1]

  dim3 blk(256);

  prep<<<dim3(2993), blk, 0, stream>>>(
      support, query, geo, Wk, Wv, Wq, Wo, Wg,
      Abf, Qbf, Gbf, Btkv, Btq, Bto, Btg, q_idx, q_start, N, Q, E);

  gemm_mfma<2, false><<<dim3(512 / 128, N / 128), blk, 0, stream>>>(
      Abf, Btkv, (void*)KV, nullptr, N, 512, D, 0);
  gemm_mfma<1, false><<<dim3(D / 128, Q / 128), blk, 0, stream>>>(
      Qbf, Btq, (void*)Qf, nullptr, Q, D, D, D);
  gemm_mfma<1, false><<<dim3(D / 128, Q / 128), blk, 0, stream>>>(
      Gbf, Btg, (void*)Gf, nullptr, Q, D, 64, D);

  edge_attn<<<dim3(Q), blk, 0, stream>>>(s_idx, q_start, (const uint4*)KV,
                                         Qf, Gf, Opre, log_tau);

  gemm_mfma<0, true><<<dim3(D / 128, Q / 128), blk, 0, stream>>>(
      Opre, Bto, d_out, bo, Q, D, D, D);
}